// Round 1
// baseline (81.774 us; speedup 1.0000x reference)
//
#include <hip/hip_runtime.h>
#include <math.h>

#define NKV    8
#define NREP   4
#define NH     32
#define BATCH  8
#define D      128
#define SEQ    4096
#define CHUNKS 32
#define CS     128          // SEQ / CHUNKS
#define PSTRIDE 130         // 128 o + m + l per (pair,chunk,rep)

// ---------------------------------------------------------------------------
// Kernel 1: partial attention per (pair = g*8+b, chunk).
// grid (64, CHUNKS), block 256 (4 waves).
// ---------------------------------------------------------------------------
__global__ __launch_bounds__(256) void attn_partial(
    const int*   __restrict__ input_pos,
    const float* __restrict__ q,
    const float* __restrict__ knew,
    const float* __restrict__ vnew,
    const float* __restrict__ kcache,
    const float* __restrict__ vcache,
    const float* __restrict__ mask,
    float*       __restrict__ ws)
{
    const int pair = blockIdx.x;      // g*8 + b
    const int c    = blockIdx.y;
    const int g    = pair >> 3;
    const int b    = pair & 7;
    const int t    = threadIdx.x;
    const int pos  = input_pos[0];

    __shared__ float sc[NREP][CS];    // scores, then probs
    __shared__ float q_lds[NREP][D];
    __shared__ float ml[NREP][2];

    // stage q for the 4 rep heads (512 floats, 2 per thread)
    #pragma unroll
    for (int i = 0; i < 2; ++i) {
        int j = t + i * 256;          // 0..511
        int r = j >> 7;
        int d = j & 127;
        q_lds[r][d] = q[((size_t)(g * NREP + r) * BATCH + b) * D + d];
    }
    __syncthreads();

    const float  scale  = 0.08838834764831845f;   // 1/sqrt(128)
    const size_t kvbase = (size_t)(g * BATCH + b) * SEQ * D;
    const float* kbase  = kcache + kvbase;
    const float* vbase  = vcache + kvbase;
    const float* mrow   = mask + (size_t)pos * SEQ;
    const float* knewr  = knew + (size_t)(g * BATCH + b) * D;
    const float* vnewr  = vnew + (size_t)(g * BATCH + b) * D;
    const int    s0     = c * CS;

    const int wave = t >> 6;
    const int lane = t & 63;
    const int half = lane >> 5;       // which of 2 rows this wave handles
    const int l32  = lane & 31;       // float4 slot within row (32*4 = 128)

    float4 qv[NREP];
    #pragma unroll
    for (int r = 0; r < NREP; ++r)
        qv[r] = *(const float4*)&q_lds[r][l32 * 4];

    // ---- phase 1: scores (reads K chunk, coalesced float4) ----
    for (int p = 0; p < CS / 8; ++p) {
        int sl = p * 8 + wave * 2 + half;
        int s  = s0 + sl;
        const float4* krow = (s == pos) ? (const float4*)knewr
                                        : (const float4*)(kbase + (size_t)s * D);
        float4 kv = krow[l32];
        float acc[NREP];
        #pragma unroll
        for (int r = 0; r < NREP; ++r)
            acc[r] = qv[r].x * kv.x + qv[r].y * kv.y + qv[r].z * kv.z + qv[r].w * kv.w;
        // reduce across the 32 lanes of this half-wave
        #pragma unroll
        for (int off = 1; off < 32; off <<= 1) {
            #pragma unroll
            for (int r = 0; r < NREP; ++r)
                acc[r] += __shfl_xor(acc[r], off);
        }
        if (l32 == 0) {
            float mval = mrow[s];
            #pragma unroll
            for (int r = 0; r < NREP; ++r)
                sc[r][sl] = acc[r] * scale + mval;
        }
    }
    __syncthreads();

    // ---- phase 1.5: per-rep local softmax (wave w owns rep r = w) ----
    {
        int r = wave;
        float v0 = sc[r][lane];
        float v1 = sc[r][lane + 64];
        float m  = fmaxf(v0, v1);
        #pragma unroll
        for (int off = 1; off < 64; off <<= 1)
            m = fmaxf(m, __shfl_xor(m, off));
        float e0 = __expf(v0 - m);
        float e1 = __expf(v1 - m);
        sc[r][lane]      = e0;
        sc[r][lane + 64] = e1;
        float l = e0 + e1;
        #pragma unroll
        for (int off = 1; off < 64; off <<= 1)
            l += __shfl_xor(l, off);
        if (lane == 0) { ml[r][0] = m; ml[r][1] = l; }
    }
    __syncthreads();

    // ---- phase 2: PV partial (reads V chunk, coalesced float2) ----
    {
        int r = t >> 6;
        int j = t & 63;               // float2 slot (64*2 = 128)
        float o0 = 0.f, o1 = 0.f;
        for (int sl = 0; sl < CS; ++sl) {
            int s = s0 + sl;
            const float* vrow = (s == pos) ? vnewr : (vbase + (size_t)s * D);
            float2 vv = ((const float2*)vrow)[j];
            float pr  = sc[r][sl];
            o0 += pr * vv.x;
            o1 += pr * vv.y;
        }
        size_t base = (((size_t)pair * CHUNKS + c) * NREP + r) * PSTRIDE;
        ws[base + j * 2]     = o0;
        ws[base + j * 2 + 1] = o1;
        if (j == 0) { ws[base + 128] = ml[r][0]; ws[base + 129] = ml[r][1]; }
    }
}

// ---------------------------------------------------------------------------
// Kernel 2: LSE-combine the 32 chunks per (pair, rep). grid 256, block 128.
// ---------------------------------------------------------------------------
__global__ __launch_bounds__(128) void attn_reduce(
    const float* __restrict__ ws, float* __restrict__ out)
{
    const int idx  = blockIdx.x;      // (pair, r)
    const int pair = idx >> 2;
    const int r    = idx & 3;
    const int g    = pair >> 3;
    const int b    = pair & 7;
    const int d    = threadIdx.x;

    float M = -INFINITY;
    for (int c = 0; c < CHUNKS; ++c) {
        size_t base = (((size_t)pair * CHUNKS + c) * NREP + r) * PSTRIDE;
        M = fmaxf(M, ws[base + 128]);
    }
    float acc = 0.f, L = 0.f;
    for (int c = 0; c < CHUNKS; ++c) {
        size_t base = (((size_t)pair * CHUNKS + c) * NREP + r) * PSTRIDE;
        float w = __expf(ws[base + 128] - M);
        acc += ws[base + d] * w;
        L   += ws[base + 129] * w;
    }
    int h = g * NREP + r;
    out[(size_t)b * (NH * D) + h * D + d] = acc / L;
}

// ---------------------------------------------------------------------------
// Fallback (ws too small): one block per (head, batch), full sequence.
// grid 256, block 256.
// ---------------------------------------------------------------------------
__global__ __launch_bounds__(256) void attn_full(
    const int*   __restrict__ input_pos,
    const float* __restrict__ q,
    const float* __restrict__ knew,
    const float* __restrict__ vnew,
    const float* __restrict__ kcache,
    const float* __restrict__ vcache,
    const float* __restrict__ mask,
    float*       __restrict__ out)
{
    const int idx = blockIdx.x;       // h*8 + b
    const int h   = idx >> 3;
    const int b   = idx & 7;
    const int g   = h >> 2;
    const int t   = threadIdx.x;
    const int wave = t >> 6, lane = t & 63, half = lane >> 5, l32 = lane & 31;
    const int pos = input_pos[0];

    __shared__ float sc[SEQ];         // 16 KB
    __shared__ float wred[4];
    __shared__ float oacc[2][D];

    const size_t kvbase = (size_t)(g * BATCH + b) * SEQ * D;
    const float* kbase  = kcache + kvbase;
    const float* vbase  = vcache + kvbase;
    const float* mrow   = mask + (size_t)pos * SEQ;
    const float* knewr  = knew + (size_t)(g * BATCH + b) * D;
    const float* vnewr  = vnew + (size_t)(g * BATCH + b) * D;
    const float  scale  = 0.08838834764831845f;

    float4 qv = ((const float4*)(q + (size_t)(h * BATCH + b) * D))[l32];

    for (int p = 0; p < SEQ / 8; ++p) {
        int s = p * 8 + wave * 2 + half;
        const float4* krow = (s == pos) ? (const float4*)knewr
                                        : (const float4*)(kbase + (size_t)s * D);
        float4 kv = krow[l32];
        float acc = qv.x * kv.x + qv.y * kv.y + qv.z * kv.z + qv.w * kv.w;
        #pragma unroll
        for (int off = 1; off < 32; off <<= 1)
            acc += __shfl_xor(acc, off);
        if (l32 == 0) sc[s] = acc * scale + mrow[s];
    }
    __syncthreads();

    float m = -INFINITY;
    for (int s = t; s < SEQ; s += 256) m = fmaxf(m, sc[s]);
    #pragma unroll
    for (int off = 1; off < 64; off <<= 1) m = fmaxf(m, __shfl_xor(m, off));
    if (lane == 0) wred[wave] = m;
    __syncthreads();
    m = fmaxf(fmaxf(wred[0], wred[1]), fmaxf(wred[2], wred[3]));
    __syncthreads();

    float l = 0.f;
    for (int s = t; s < SEQ; s += 256) { float e = __expf(sc[s] - m); sc[s] = e; l += e; }
    #pragma unroll
    for (int off = 1; off < 64; off <<= 1) l += __shfl_xor(l, off);
    __syncthreads();
    if (lane == 0) wred[wave] = l;
    __syncthreads();
    float L = wred[0] + wred[1] + wred[2] + wred[3];

    {
        int hf = t >> 7, d = t & 127;
        float acc = 0.f;
        for (int s = hf * (SEQ / 2); s < (hf + 1) * (SEQ / 2); ++s) {
            const float* vrow = (s == pos) ? vnewr : (vbase + (size_t)s * D);
            acc += sc[s] * vrow[d];
        }
        oacc[hf][d] = acc;
    }
    __syncthreads();
    if (t < D) out[(size_t)b * (NH * D) + h * D + t] = (oacc[0][t] + oacc[1][t]) / L;
}

extern "C" void kernel_launch(void* const* d_in, const int* in_sizes, int n_in,
                              void* d_out, int out_size, void* d_ws, size_t ws_size,
                              hipStream_t stream) {
    const int*   input_pos = (const int*)  d_in[0];
    const float* q         = (const float*)d_in[1];
    const float* k         = (const float*)d_in[2];
    const float* v         = (const float*)d_in[3];
    const float* kcache    = (const float*)d_in[4];
    const float* vcache    = (const float*)d_in[5];
    const float* mask      = (const float*)d_in[6];
    float* out = (float*)d_out;

    const size_t need = (size_t)64 * CHUNKS * NREP * PSTRIDE * sizeof(float);
    if (ws_size >= need) {
        dim3 g1(64, CHUNKS);
        attn_partial<<<g1, 256, 0, stream>>>(input_pos, q, k, v, kcache, vcache, mask,
                                             (float*)d_ws);
        attn_reduce<<<256, 128, 0, stream>>>((const float*)d_ws, out);
    } else {
        attn_full<<<256, 256, 0, stream>>>(input_pos, q, k, v, kcache, vcache, mask, out);
    }
}